// Round 11
// baseline (181.721 us; speedup 1.0000x reference)
//
#include <hip/hip_runtime.h>
#include <cfloat>
#include <math.h>

#define NB 8
#define NPT 4096
#define NC 64
#define KNN 20
#define KSZ 16
#define BPTS 8

typedef __attribute__((ext_vector_type(8))) short short8;
typedef __attribute__((ext_vector_type(4))) float f32x4;
typedef __attribute__((ext_vector_type(2))) float f32x2;

// ---------- helpers ----------
__device__ __forceinline__ unsigned short f2bf(float f) {
  unsigned u = __float_as_uint(f);
  unsigned r = (u + 0x7fffu + ((u >> 16) & 1u)) >> 16;
  return (unsigned short)r;
}
__device__ __forceinline__ float bf2f(unsigned short h) {
  return __uint_as_float(((unsigned)h) << 16);
}

// packed f32 fma with op_sel splats (VOP3P). IEEE f32 fma per half.
__device__ __forceinline__ f32x2 pk_fma_zw(f32x2 a, f32x2 zw) {
  f32x2 d;
  asm("v_pk_fma_f32 %0, %1, %2, %2 op_sel:[0,0,1] op_sel_hi:[1,0,1]"
      : "=v"(d) : "v"(a), "v"(zw));
  return d;
}
__device__ __forceinline__ f32x2 pk_fma_s1hi(f32x2 a, f32x2 b, f32x2 c) {
  f32x2 d;
  asm("v_pk_fma_f32 %0, %1, %2, %3 op_sel:[0,1,0] op_sel_hi:[1,1,1]"
      : "=v"(d) : "v"(a), "v"(b), "v"(c));
  return d;
}
__device__ __forceinline__ f32x2 pk_fma_s1lo(f32x2 a, f32x2 b, f32x2 c) {
  f32x2 d;
  asm("v_pk_fma_f32 %0, %1, %2, %3 op_sel:[0,0,0] op_sel_hi:[1,0,1]"
      : "=v"(d) : "v"(a), "v"(b), "v"(c));
  return d;
}

// ---------- K0: merged prep (pack_cw | pack_cw2 | transpose_ft) ----------
__global__ void k_prep(const float* __restrict__ cw, const float* __restrict__ mlp_w,
                       const float* __restrict__ mlp_b, const float* __restrict__ f,
                       unsigned short* __restrict__ bp, unsigned short* __restrict__ bp2,
                       unsigned short* __restrict__ ft) {
  __shared__ float tile[64][65];
  int blk = blockIdx.x;
  if (blk < 256) {
    // conv_w lower half [64][0..1023] -> bpk B-frag bf16 (K=1024)
    int t = blk * 256 + threadIdx.x;  // 65536
    int j = t & 7, lane = (t >> 3) & 63, nt = (t >> 9) & 3, ks = t >> 11;
    int k = ks * 32 + ((lane >> 4) << 3) + j;
    int o = nt * 16 + (lane & 15);
    bp[t] = f2bf(cw[o * 2048 + k]);
  } else if (blk < 288) {
    // folded x_feats weights -> bpk2 B-frag bf16 (K=128)
    int t = (blk - 256) * 256 + threadIdx.x;  // 8192
    int jj = t & 7, lane = (t >> 3) & 63, nt = (t >> 9) & 3, ks2 = t >> 11;
    int k = ks2 * 32 + ((lane >> 4) << 3) + jj;
    int s = k >> 3, j = k & 7;
    int o = nt * 16 + (lane & 15);
    float acc = 0.0f;
    for (int c = 0; c < 64; ++c) {
      float coef = (j < 7) ? mlp_w[c * 7 + j] : mlp_b[c];
      acc = fmaf(cw[o * 2048 + 1024 + c * 16 + s], coef, acc);
    }
    bp2[t] = f2bf(acc);
  } else {
    // feature [B][C][N] -> ftT [B][N][C] bf16
    int blk3 = blk - 288;  // 0..511
    int b = blk3 >> 6;
    int n0 = (blk3 & 63) * 64;
    int lane = threadIdx.x & 63;
    int rr = threadIdx.x >> 6;  // 0..3
#pragma unroll
    for (int c0 = 0; c0 < 64; c0 += 4) {
      int c = c0 + rr;
      tile[c][lane] = f[(b * 64 + c) * 4096 + n0 + lane];
    }
    __syncthreads();
#pragma unroll
    for (int m0 = 0; m0 < 64; m0 += 4) {
      int nn = m0 + rr;
      ft[(b * 4096 + n0 + nn) * 64 + lane] = f2bf(tile[lane][nn]);
    }
  }
}

// ---------- K1: KNN v7 ----------
// One wave per 4 rows. Pass1: pk_fma per-lane min; FULL bitonic -> T = exact
// pk-rank-24 of lane minima (>= f32 rank-24 of row). Pass2: identical pk chain,
// ballot count + DIRECT ds_write_b16 list collection (no permute round-trip).
// Exact f64 lex rank via readlane broadcast; slot = rank (self = rank 0).
// Fallback to full exact scan on overflow / self-missing.

__device__ __noinline__ void knn_full(const float4* __restrict__ pts, int n, int lane,
                                      int g, int* __restrict__ idxOut) {
  const int M = 24;
  float4 qp = pts[n];
  float qx = qp.x, qy = qp.y, qz = qp.z;
  float v[M];
  int id[M];
#pragma unroll
  for (int r = 0; r < M; ++r) { v[r] = FLT_MAX; id[r] = 0x7fffffff; }
  for (int i = 0; i < 64; ++i) {
    int j = (i << 6) | lane;
    float4 p = pts[j];
    float dx = p.x - qx, dy = p.y - qy, dz = p.z - qz;
    float d2 = fmaf(dx, dx, fmaf(dy, dy, dz * dz));
    bool c[M];
#pragma unroll
    for (int r = 0; r < M; ++r) c[r] = d2 < v[r];
#pragma unroll
    for (int r = M - 1; r >= 1; --r) {
      v[r] = c[r - 1] ? v[r - 1] : (c[r] ? d2 : v[r]);
      id[r] = c[r - 1] ? id[r - 1] : (c[r] ? j : id[r]);
    }
    v[0] = c[0] ? d2 : v[0];
    id[0] = c[0] ? j : id[0];
  }
  unsigned long long key = ((unsigned long long)__float_as_uint(v[0]) << 32) | (unsigned)id[0];
  unsigned long long ext = ~0ull;
  for (int r = 0; r < 24; ++r) {
    unsigned long long k = key;
#pragma unroll
    for (int s = 1; s < 64; s <<= 1) {
      unsigned long long o = __shfl_xor(k, s, 64);
      k = (o < k) ? o : k;
    }
    if (lane == r) ext = k;
    if (key == k) {
#pragma unroll
      for (int q = 0; q < M - 1; ++q) { v[q] = v[q + 1]; id[q] = id[q + 1]; }
      v[M - 1] = FLT_MAX;
      id[M - 1] = 0x7fffffff;
      key = ((unsigned long long)__float_as_uint(v[0]) << 32) | (unsigned)id[0];
    }
  }
  int ei = (int)(unsigned)(ext & 0xffffffffu);
  bool al = lane < 24;
  double dv = -1.0;
  if (al) {
    float4 p = pts[ei];
    double dx = (double)p.x - (double)qx;
    double dy = (double)p.y - (double)qy;
    double dz = (double)p.z - (double)qz;
    dv = dx * dx + dy * dy + dz * dz;
  }
#pragma unroll
  for (int r = 0; r < 4; ++r) {
    double bd = al ? dv : -1.0;
    int bi = al ? ei : -1;
#pragma unroll
    for (int s = 1; s < 64; s <<= 1) {
      double od = __shfl_xor(bd, s, 64);
      int oi = __shfl_xor(bi, s, 64);
      if (od > bd || (od == bd && oi > bi)) { bd = od; bi = oi; }
    }
    if (al && ei == bi) al = false;
  }
  unsigned long long msk = __ballot(al && ei != n);
  if (al) {
    if (ei == n) {
      idxOut[g * 20] = n;
    } else {
      int pos = 1 + __popcll(msk & ((1ull << lane) - 1ull));
      idxOut[g * 20 + pos] = ei;
    }
  }
}

__launch_bounds__(1024, 2)
__global__ void k_knn(const float* __restrict__ x, int* __restrict__ idxOut) {
  __shared__ float4 pts[4096];               // 64KB: (x,y,z,xx)
  __shared__ unsigned short listL[64 * 64];  // 8KB: per-row compacted candidates
  int b = blockIdx.x >> 6;  // 64 blocks/batch, 64 rows/block
  const float* xb = x + b * 3 * 4096;
  for (int i = threadIdx.x; i < 4096; i += 1024) {
    float px = xb[i], py = xb[4096 + i], pz = xb[8192 + i];
    pts[i] = make_float4(px, py, pz, fmaf(px, px, fmaf(py, py, pz * pz)));
  }
  __syncthreads();

  int lane = threadIdx.x & 63;
  int w = threadIdx.x >> 6;
  int row = w << 2;                              // block-local first row
  int nb = ((blockIdx.x & 63) << 6) + row;       // global first row
  int gb = b * 4096 + nb;

  float4 q0 = pts[nb], q1 = pts[nb + 1], q2 = pts[nb + 2], q3 = pts[nb + 3];
  f32x2 m2x01 = {-2.0f * q0.x, -2.0f * q1.x};
  f32x2 m2y01 = {-2.0f * q0.y, -2.0f * q1.y};
  f32x2 m2z01 = {-2.0f * q0.z, -2.0f * q1.z};
  f32x2 m2x23 = {-2.0f * q2.x, -2.0f * q3.x};
  f32x2 m2y23 = {-2.0f * q2.y, -2.0f * q3.y};
  f32x2 m2z23 = {-2.0f * q2.z, -2.0f * q3.z};

  // ---- pass 1: per-lane min for 4 rows, packed f32 ----
  float v0 = FLT_MAX, v1 = FLT_MAX, v2 = FLT_MAX, v3 = FLT_MAX;
#pragma unroll 4
  for (int i = 0; i < 64; ++i) {
    float4 p = pts[(i << 6) | lane];
    f32x2 pxy = {p.x, p.y}, pzw = {p.z, p.w};
    f32x2 t0 = pk_fma_zw(m2z01, pzw);
    f32x2 t1 = pk_fma_zw(m2z23, pzw);
    t0 = pk_fma_s1hi(m2y01, pxy, t0);
    t1 = pk_fma_s1hi(m2y23, pxy, t1);
    t0 = pk_fma_s1lo(m2x01, pxy, t0);
    t1 = pk_fma_s1lo(m2x23, pxy, t1);
    v0 = fminf(v0, t0[0]);
    v1 = fminf(v1, t0[1]);
    v2 = fminf(v2, t1[0]);
    v3 = fminf(v3, t1[1]);
  }

  // ---- FULL bitonic sort of the 64 lane minima (ascending) ----
#pragma unroll
  for (int k = 2; k <= 64; k <<= 1) {
#pragma unroll
    for (int j = k >> 1; j > 0; j >>= 1) {
      bool sel = ((lane & k) == 0) == ((lane & j) == 0);
      {
        float o = __shfl_xor(v0, j, 64);
        v0 = sel ? fminf(v0, o) : fmaxf(v0, o);
      }
      {
        float o = __shfl_xor(v1, j, 64);
        v1 = sel ? fminf(v1, o) : fmaxf(v1, o);
      }
      {
        float o = __shfl_xor(v2, j, 64);
        v2 = sel ? fminf(v2, o) : fmaxf(v2, o);
      }
      {
        float o = __shfl_xor(v3, j, 64);
        v3 = sel ? fminf(v3, o) : fmaxf(v3, o);
      }
    }
  }
  float T0 = __shfl(v0, 23, 64);  // exact pk-rank-24 of lane minima
  float T1 = __shfl(v1, 23, 64);
  float T2 = __shfl(v2, 23, 64);
  float T3 = __shfl(v3, 23, 64);

  // ---- pass 2: identical pk chain; ballot count + direct ds_write collect ----
  int base0 = 0, base1 = 0, base2 = 0, base3 = 0;
  bool ovf0 = false, ovf1 = false, ovf2 = false, ovf3 = false;
#pragma unroll 2
  for (int i = 0; i < 64; ++i) {
    int j = (i << 6) | lane;
    float4 p = pts[j];
    f32x2 pxy = {p.x, p.y}, pzw = {p.z, p.w};
    f32x2 t0 = pk_fma_zw(m2z01, pzw);
    f32x2 t1 = pk_fma_zw(m2z23, pzw);
    t0 = pk_fma_s1hi(m2y01, pxy, t0);
    t1 = pk_fma_s1hi(m2y23, pxy, t1);
    t0 = pk_fma_s1lo(m2x01, pxy, t0);
    t1 = pk_fma_s1lo(m2x23, pxy, t1);
    {
      bool pred = (t0[0] <= T0);
      unsigned long long mask = __ballot(pred);
      if (mask) {
        int cnt = __popcll(mask);
        if (base0 + cnt > 64) {
          ovf0 = true;
        } else if (pred) {
          int dst = base0 + __popcll(mask & ((1ull << lane) - 1ull));
          listL[(row << 6) + dst] = (unsigned short)j;
        }
        base0 += cnt;
      }
    }
    {
      bool pred = (t0[1] <= T1);
      unsigned long long mask = __ballot(pred);
      if (mask) {
        int cnt = __popcll(mask);
        if (base1 + cnt > 64) {
          ovf1 = true;
        } else if (pred) {
          int dst = base1 + __popcll(mask & ((1ull << lane) - 1ull));
          listL[((row + 1) << 6) + dst] = (unsigned short)j;
        }
        base1 += cnt;
      }
    }
    {
      bool pred = (t1[0] <= T2);
      unsigned long long mask = __ballot(pred);
      if (mask) {
        int cnt = __popcll(mask);
        if (base2 + cnt > 64) {
          ovf2 = true;
        } else if (pred) {
          int dst = base2 + __popcll(mask & ((1ull << lane) - 1ull));
          listL[((row + 2) << 6) + dst] = (unsigned short)j;
        }
        base2 += cnt;
      }
    }
    {
      bool pred = (t1[1] <= T3);
      unsigned long long mask = __ballot(pred);
      if (mask) {
        int cnt = __popcll(mask);
        if (base3 + cnt > 64) {
          ovf3 = true;
        } else if (pred) {
          int dst = base3 + __popcll(mask & ((1ull << lane) - 1ull));
          listL[((row + 3) << 6) + dst] = (unsigned short)j;
        }
        base3 += cnt;
      }
    }
  }

  // ---- exact f64 lex rank (readlane broadcast, 4 rows fused) ----
  // DS ops are in-order per wave: our listL writes are visible to our reads.
  int c[4], e[4];
  c[0] = ovf0 ? 0 : base0;
  c[1] = ovf1 ? 0 : base1;
  c[2] = ovf2 ? 0 : base2;
  c[3] = ovf3 ? 0 : base3;
  int rank0 = 0, rank1 = 0, rank2 = 0, rank3 = 0;
  double dm[4];
#pragma unroll
  for (int r = 0; r < 4; ++r) {
    int e_ = (lane < c[r]) ? (int)listL[((row + r) << 6) + lane] : 0;
    e[r] = e_;
    float4 pp = pts[e_];
    float4 qq = pts[nb + r];
    double dx = (double)pp.x - (double)qq.x;
    double dy = (double)pp.y - (double)qq.y;
    double dz = (double)pp.z - (double)qq.z;
    dm[r] = dx * dx + dy * dy + dz * dz;
  }
  int cmax = max(max(c[0], c[1]), max(c[2], c[3]));
  for (int it = 0; it < cmax; ++it) {
#pragma unroll
    for (int r = 0; r < 4; ++r) {
      int lo = __builtin_amdgcn_readlane(__double2loint(dm[r]), it);
      int hi = __builtin_amdgcn_readlane(__double2hiint(dm[r]), it);
      int ir = __builtin_amdgcn_readlane(e[r], it);
      double dr = __hiloint2double(hi, lo);
      bool less = (it < c[r]) && ((dr < dm[r]) || (dr == dm[r] && ir < e[r]));
      int inc = (lane < c[r] && less) ? 1 : 0;
      if (r == 0) rank0 += inc;
      else if (r == 1) rank1 += inc;
      else if (r == 2) rank2 += inc;
      else rank3 += inc;
    }
  }
#pragma unroll
  for (int r = 0; r < 4; ++r) {
    int rk = (r == 0) ? rank0 : (r == 1) ? rank1 : (r == 2) ? rank2 : rank3;
    bool kept = (lane < c[r]) && (rk < 20);
    bool selfk = kept && (e[r] == nb + r);
    if (__ballot(selfk) != 0ull) {
      if (kept) idxOut[(gb + r) * 20 + rk] = e[r];
    } else {
      knn_full(pts, nb + r, lane, gb + r, idxOut);
    }
  }
}

// ---------- K2: fused features + aw(bf16 B-frag) + MFMA agg + MFMA conv ----------
#define AGG_OFF 0            // bf16 agg[8][1024], 16KB; reused as f32 red
#define AWB_OFF 16384        // bf16 awB[8][512]  B-frag (32k x 16s per pt), 8KB
#define FPA_OFF 24576        // bf16 fpA[16][128] F' A-tile, 4KB
#define F7S_OFF 28672        // float4 f7s[8][20], 2560B
#define QL_OFF  31232        // float4 qL[8], 128B
#define IDX_OFF 31360        // int idxL[8][20], 640B
#define SMEM_SZ 33792        // 33KB total

__launch_bounds__(256, 4)
__global__ void k_main(const float* __restrict__ x, const float* __restrict__ feat,
                       const unsigned short* __restrict__ ftT, int useFtT,
                       const float* __restrict__ kern,
                       const unsigned short* __restrict__ bpk,
                       const unsigned short* __restrict__ bpk2,
                       const float* __restrict__ conv_b, const int* __restrict__ idxIn,
                       float* __restrict__ out) {
  __shared__ __align__(16) unsigned char smem[SMEM_SZ];
  unsigned short* agg = (unsigned short*)(smem + AGG_OFF);
  unsigned short* awB = (unsigned short*)(smem + AWB_OFF);
  float4* f7s = (float4*)(smem + F7S_OFF);
  float4* qL = (float4*)(smem + QL_OFF);
  int* idxL = (int*)(smem + IDX_OFF);

  int t = threadIdx.x;
  int lane = t & 63;
  int w = t >> 6;
  int b = blockIdx.x & 7;
  int n0 = (blockIdx.x >> 3) * BPTS;
  int g0 = b * 4096 + n0;
  const float* xb = x + b * 3 * 4096;

  // ---- step 0: geometry (8 pts x 20 nbrs) ----
  {
    int pt = t >> 5, slot = t & 31;
    int n = n0 + pt;
    float qx = xb[n], qy = xb[4096 + n], qz = xb[8192 + n];
    if (slot < 20) {
      int kk = idxIn[(g0 + pt) * 20 + slot];
      idxL[pt * 20 + slot] = kk;
      float rx = xb[kk] - qx, ry = xb[4096 + kk] - qy, rz = xb[8192 + kk] - qz;
      float ds = sqrtf(rx * rx + ry * ry + rz * rz);
      f7s[pt * 20 + slot] = make_float4(rx, ry, rz, ds);
    } else if (slot == 20) {
      qL[pt] = make_float4(qx, qy, qz, 0.0f);
    }
  }
  __syncthreads();

  // ---- step 1: aw chain -> awB bf16 B-frag + F' build (128 thr: (pt,s)) ----
  if (t < 128) {
    int pt = t >> 4, s = t & 15;
    float kx = kern[s], ky = kern[16 + s], kz = kern[32 + s];
    float wv[20];
#pragma unroll
    for (int k = 0; k < 20; ++k) {
      float4 f = f7s[pt * 20 + k];
      float dot = f.x * kx + f.y * ky + f.z * kz;
      if (s == 0 && k == 0) dot += 1.0f;
      wv[k] = dot > 0.0f ? dot : 0.0f;
    }
    float sum = 0.0f;
#pragma unroll
    for (int k = 0; k < 20; ++k) sum += wv[k];
    float inv1 = 1.0f / (sum + 1e-6f);
    float sum2 = 0.0f;
#pragma unroll
    for (int k = 0; k < 20; ++k) {
      float u = wv[k] * inv1;
      sum2 += u * u;
    }
    float inv2 = 1.0f / (sum2 + 1e-6f);
    float colsum = 0.0f;
    float F0 = 0.0f, F1 = 0.0f, F2 = 0.0f, F3 = 0.0f;
    unsigned short* awp = awB + pt * 512;
#pragma unroll
    for (int k = 0; k < 20; ++k) {
      float u = wv[k] * inv1;
      u = u * u * inv2;
      u = (u > 0.1f) ? u : 0.0f;
      awp[(((k >> 3) * 16 + s) << 3) + (k & 7)] = f2bf(u);
      colsum += u;
      float4 f = f7s[pt * 20 + k];
      F0 = fmaf(f.x, u, F0);
      F1 = fmaf(f.y, u, F1);
      F2 = fmaf(f.z, u, F2);
      F3 = fmaf(f.w, u, F3);
    }
#pragma unroll
    for (int k = 20; k < 32; ++k)
      awp[(((k >> 3) * 16 + s) << 3) + (k & 7)] = 0;
    float4 q = qL[pt];
    __align__(16) unsigned short tmp[8];
    tmp[0] = f2bf(q.x * colsum);
    tmp[1] = f2bf(q.y * colsum);
    tmp[2] = f2bf(q.z * colsum);
    tmp[3] = f2bf(F0);
    tmp[4] = f2bf(F1);
    tmp[5] = f2bf(F2);
    tmp[6] = f2bf(F3);
    tmp[7] = f2bf(colsum);
    *(uint4*)(smem + FPA_OFF + pt * 256 + ((s ^ (pt & 7)) << 4)) = *(uint4*)tmp;
  }
  __syncthreads();

  // ---- agg via MFMA: per pt, [64c x 32k(pad)] x [32k x 16s] ----
  {
    int r15 = lane & 15, chunk = lane >> 4;
#pragma unroll
    for (int half = 0; half < 2; ++half) {
      int pt = (w << 1) + half;
      int nofs[8];
#pragma unroll
      for (int j = 0; j < 8; ++j) {
        int k = (chunk << 3) + j;
        nofs[j] = (k < 20) ? ((b * 4096 + idxL[pt * 20 + k]) << 6) : -1;
      }
      short8 bfrag = *(const short8*)(awB + pt * 512 + (lane << 3));
      f32x4 accA[4];
#pragma unroll
      for (int ct = 0; ct < 4; ++ct) accA[ct] = (f32x4){0.f, 0.f, 0.f, 0.f};
#pragma unroll
      for (int ct = 0; ct < 4; ++ct) {
        int c = (ct << 4) + r15;
        union { short8 v; unsigned short u[8]; } af;
#pragma unroll
        for (int j = 0; j < 8; ++j) {
          unsigned short val = 0;
          if (nofs[j] >= 0) {
            if (useFtT) val = ftT[nofs[j] + c];
            else val = f2bf(feat[(b * 64 + c) * 4096 + (nofs[j] >> 6) - b * 4096]);
          }
          af.u[j] = val;
        }
        accA[ct] = __builtin_amdgcn_mfma_f32_16x16x32_bf16(af.v, bfrag, accA[ct], 0, 0, 0);
      }
      char* rb = (char*)(smem + AGG_OFF) + pt * 2048;
      int sw = (pt & 7) << 4;
#pragma unroll
      for (int ct = 0; ct < 4; ++ct)
#pragma unroll
        for (int q = 0; q < 4; ++q) {
          int kidx = (((ct << 4) + (chunk << 2) + q) << 4) + r15;
          *(unsigned short*)(rb + ((kidx << 1) ^ sw)) = f2bf(accA[ct][q]);
        }
    }
  }
  __syncthreads();

  // ---- conv GEMM: K=1024 (agg) + K=128 (F') ----
  f32x4 acc[4];
#pragma unroll
  for (int nt = 0; nt < 4; ++nt) acc[nt] = (f32x4){0.f, 0.f, 0.f, 0.f};
  {
    int r = lane & 15;
    const char* rowbase = (const char*)(smem + AGG_OFF) + r * 2048;
#pragma unroll
    for (int ks = 0; ks < 8; ++ks) {
      int ksl = w * 8 + ks;
      int off = (ksl * 64 + ((lane >> 4) << 4)) ^ ((r & 7) << 4);
      short8 af = *(const short8*)(rowbase + off);
#pragma unroll
      for (int nt = 0; nt < 4; ++nt) {
        short8 bf = *(const short8*)(bpk + (((ksl * 4 + nt) * 64 + lane) << 3));
        acc[nt] = __builtin_amdgcn_mfma_f32_16x16x32_bf16(af, bf, acc[nt], 0, 0, 0);
      }
    }
    {
      int chunk = (w << 2) + (lane >> 4);  // 0..15
      short8 af = *(const short8*)(smem + FPA_OFF + r * 256 + ((chunk ^ (r & 7)) << 4));
#pragma unroll
      for (int nt = 0; nt < 4; ++nt) {
        short8 bf = *(const short8*)(bpk2 + ((((w << 2) + nt) * 64 + lane) << 3));
        acc[nt] = __builtin_amdgcn_mfma_f32_16x16x32_bf16(af, bf, acc[nt], 0, 0, 0);
      }
    }
  }
  __syncthreads();  // before reusing agg as red

  // ---- cross-wave reduce ----
  float* red = (float*)(smem + AGG_OFF);  // 8KB of 16KB
  {
#pragma unroll
    for (int nt = 0; nt < 4; ++nt)
#pragma unroll
      for (int r = 0; r < 4; ++r) {
        int row = ((lane >> 4) << 2) + r;  // 0..15; only 0..7 valid
        if (row < 8) {
          int o = nt * 16 + (lane & 15);
          red[(w * 8 + row) * 64 + (o ^ ((row & 7) << 2))] = acc[nt][r];
        }
      }
  }
  __syncthreads();
#pragma unroll
  for (int rep = 0; rep < 2; ++rep) {
    int u = rep * 256 + t;
    int pt = u & 7, o = u >> 3;
    float s = conv_b[o];
#pragma unroll
    for (int w2 = 0; w2 < 4; ++w2) s += red[(w2 * 8 + pt) * 64 + (o ^ ((pt & 7) << 2))];
    out[(b * 64 + o) * 4096 + n0 + pt] = s;
  }
}

// ---------- K3a: BN stats stage 1 (512 blocks) ----------
__global__ void k_bnstats1(const float* __restrict__ out, double* __restrict__ partial) {
  __shared__ double rs[256], rq[256];
  int o = blockIdx.x & 63, b = blockIdx.x >> 6;
  const float* p = out + (b * 64 + o) * 4096;
  double s = 0.0, q = 0.0;
  for (int i = threadIdx.x; i < 4096; i += 256) {
    double v = (double)p[i];
    s += v;
    q += v * v;
  }
  rs[threadIdx.x] = s;
  rq[threadIdx.x] = q;
  __syncthreads();
  for (int st = 128; st > 0; st >>= 1) {
    if ((int)threadIdx.x < st) {
      rs[threadIdx.x] += rs[threadIdx.x + st];
      rq[threadIdx.x] += rq[threadIdx.x + st];
    }
    __syncthreads();
  }
  if (threadIdx.x == 0) {
    partial[(o * 8 + b) * 2] = rs[0];
    partial[(o * 8 + b) * 2 + 1] = rq[0];
  }
}

// ---------- K3b: BN apply with inline stage-2 (each block = one channel o) ----------
__global__ void k_bnapply(float* __restrict__ out, const double* __restrict__ partial,
                          const float* __restrict__ gamma, const float* __restrict__ beta) {
  __shared__ float sc_sh[2];
  int o = (blockIdx.x >> 2) & 63;  // each block's 256 float4s lie in one channel
  if (threadIdx.x == 0) {
    double s = 0.0, q = 0.0;
#pragma unroll
    for (int b = 0; b < 8; ++b) {
      s += partial[(o * 8 + b) * 2];
      q += partial[(o * 8 + b) * 2 + 1];
    }
    double mean = s / 32768.0;
    double var = q / 32768.0 - mean * mean;
    double inv = 1.0 / sqrt(var + 1e-5);
    double sc = (double)gamma[o] * inv;
    sc_sh[0] = (float)sc;
    sc_sh[1] = (float)((double)beta[o] - mean * sc);
  }
  __syncthreads();
  int i4 = blockIdx.x * 256 + threadIdx.x;  // 524288 float4s
  float sc = sc_sh[0], sh = sc_sh[1];
  float4 v = ((const float4*)out)[i4];
  v.x = fmaf(v.x, sc, sh);
  v.y = fmaf(v.y, sc, sh);
  v.z = fmaf(v.z, sc, sh);
  v.w = fmaf(v.w, sc, sh);
  ((float4*)out)[i4] = v;
}

extern "C" void kernel_launch(void* const* d_in, const int* in_sizes, int n_in,
                              void* d_out, int out_size, void* d_ws, size_t ws_size,
                              hipStream_t stream) {
  const float* x = (const float*)d_in[0];
  const float* feat = (const float*)d_in[1];
  const float* kern = (const float*)d_in[2];
  const float* mlp_w = (const float*)d_in[3];
  const float* mlp_b = (const float*)d_in[4];
  const float* conv_w = (const float*)d_in[5];
  const float* conv_b = (const float*)d_in[6];
  const float* gamma = (const float*)d_in[7];
  const float* beta = (const float*)d_in[8];
  float* out = (float*)d_out;
  char* ws = (char*)d_ws;

  // workspace layout
  int* idx = (int*)ws;                                    // 0 .. 2,621,440
  double* partial = (double*)(ws + 2621440);              // 8,192 B
  unsigned short* bpk = (unsigned short*)(ws + 2633728);  // 131,072 B (K=1024)
  unsigned short* bpk2 = (unsigned short*)(ws + 2764800); // 16,384 B  (K=128)
  unsigned short* ftT = (unsigned short*)(ws + 2781184);  // 4,194,304 B
  int useFtT = (ws_size >= (size_t)(2781184 + 4194304)) ? 1 : 0;

  k_prep<<<800, 256, 0, stream>>>(conv_w, mlp_w, mlp_b, feat, bpk, bpk2, ftT);
  k_knn<<<512, 1024, 0, stream>>>(x, idx);
  k_main<<<4096, 256, 0, stream>>>(x, feat, ftT, useFtT, kern, bpk, bpk2,
                                   conv_b, idx, out);
  k_bnstats1<<<512, 256, 0, stream>>>(out, partial);
  k_bnapply<<<2048, 256, 0, stream>>>(out, partial, gamma, beta);
}

// Round 12
// 171.984 us; speedup vs baseline: 1.0566x; 1.0566x over previous
//
#include <hip/hip_runtime.h>
#include <cfloat>
#include <math.h>

#define NB 8
#define NPT 4096
#define NC 64
#define KNN 20
#define KSZ 16
#define BPTS 8

typedef __attribute__((ext_vector_type(8))) short short8;
typedef __attribute__((ext_vector_type(4))) float f32x4;
typedef __attribute__((ext_vector_type(2))) float f32x2;

// ---------- helpers ----------
__device__ __forceinline__ unsigned short f2bf(float f) {
  unsigned u = __float_as_uint(f);
  unsigned r = (u + 0x7fffu + ((u >> 16) & 1u)) >> 16;
  return (unsigned short)r;
}
__device__ __forceinline__ float bf2f(unsigned short h) {
  return __uint_as_float(((unsigned)h) << 16);
}

// packed f32 fma with op_sel splats (VOP3P). IEEE f32 fma per half.
__device__ __forceinline__ f32x2 pk_fma_zw(f32x2 a, f32x2 zw) {
  f32x2 d;
  asm("v_pk_fma_f32 %0, %1, %2, %2 op_sel:[0,0,1] op_sel_hi:[1,0,1]"
      : "=v"(d) : "v"(a), "v"(zw));
  return d;
}
__device__ __forceinline__ f32x2 pk_fma_s1hi(f32x2 a, f32x2 b, f32x2 c) {
  f32x2 d;
  asm("v_pk_fma_f32 %0, %1, %2, %3 op_sel:[0,1,0] op_sel_hi:[1,1,1]"
      : "=v"(d) : "v"(a), "v"(b), "v"(c));
  return d;
}
__device__ __forceinline__ f32x2 pk_fma_s1lo(f32x2 a, f32x2 b, f32x2 c) {
  f32x2 d;
  asm("v_pk_fma_f32 %0, %1, %2, %3 op_sel:[0,0,0] op_sel_hi:[1,0,1]"
      : "=v"(d) : "v"(a), "v"(b), "v"(c));
  return d;
}

// ---------- K1: KNN v8 (R10 core) + merged prep blocks ----------
// Blocks 0..511: one wave per 4 rows. Pass1: pk_fma per-lane min; FULL bitonic
// -> T = exact pk-rank-24 of lane minima. Pass2: identical pk chain, ballot +
// ds_permute compaction (R10-validated). Exact f64 lex rank via readlane;
// slot = rank (self = rank 0). Fallback to full exact scan if needed.
// Blocks 512..711: prep work (pack_cw | pack_cw2 | transpose_ft), 4 virtual
// 256-thread sub-blocks each, LDS aliased onto the pts array.

__device__ __noinline__ void knn_full(const float4* __restrict__ pts, int n, int lane,
                                      int g, int* __restrict__ idxOut) {
  const int M = 24;
  float4 qp = pts[n];
  float qx = qp.x, qy = qp.y, qz = qp.z;
  float v[M];
  int id[M];
#pragma unroll
  for (int r = 0; r < M; ++r) { v[r] = FLT_MAX; id[r] = 0x7fffffff; }
  for (int i = 0; i < 64; ++i) {
    int j = (i << 6) | lane;
    float4 p = pts[j];
    float dx = p.x - qx, dy = p.y - qy, dz = p.z - qz;
    float d2 = fmaf(dx, dx, fmaf(dy, dy, dz * dz));
    bool c[M];
#pragma unroll
    for (int r = 0; r < M; ++r) c[r] = d2 < v[r];
#pragma unroll
    for (int r = M - 1; r >= 1; --r) {
      v[r] = c[r - 1] ? v[r - 1] : (c[r] ? d2 : v[r]);
      id[r] = c[r - 1] ? id[r - 1] : (c[r] ? j : id[r]);
    }
    v[0] = c[0] ? d2 : v[0];
    id[0] = c[0] ? j : id[0];
  }
  unsigned long long key = ((unsigned long long)__float_as_uint(v[0]) << 32) | (unsigned)id[0];
  unsigned long long ext = ~0ull;
  for (int r = 0; r < 24; ++r) {
    unsigned long long k = key;
#pragma unroll
    for (int s = 1; s < 64; s <<= 1) {
      unsigned long long o = __shfl_xor(k, s, 64);
      k = (o < k) ? o : k;
    }
    if (lane == r) ext = k;
    if (key == k) {
#pragma unroll
      for (int q = 0; q < M - 1; ++q) { v[q] = v[q + 1]; id[q] = id[q + 1]; }
      v[M - 1] = FLT_MAX;
      id[M - 1] = 0x7fffffff;
      key = ((unsigned long long)__float_as_uint(v[0]) << 32) | (unsigned)id[0];
    }
  }
  int ei = (int)(unsigned)(ext & 0xffffffffu);
  bool al = lane < 24;
  double dv = -1.0;
  if (al) {
    float4 p = pts[ei];
    double dx = (double)p.x - (double)qx;
    double dy = (double)p.y - (double)qy;
    double dz = (double)p.z - (double)qz;
    dv = dx * dx + dy * dy + dz * dz;
  }
#pragma unroll
  for (int r = 0; r < 4; ++r) {
    double bd = al ? dv : -1.0;
    int bi = al ? ei : -1;
#pragma unroll
    for (int s = 1; s < 64; s <<= 1) {
      double od = __shfl_xor(bd, s, 64);
      int oi = __shfl_xor(bi, s, 64);
      if (od > bd || (od == bd && oi > bi)) { bd = od; bi = oi; }
    }
    if (al && ei == bi) al = false;
  }
  unsigned long long msk = __ballot(al && ei != n);
  if (al) {
    if (ei == n) {
      idxOut[g * 20] = n;
    } else {
      int pos = 1 + __popcll(msk & ((1ull << lane) - 1ull));
      idxOut[g * 20 + pos] = ei;
    }
  }
}

__launch_bounds__(1024, 2)
__global__ void k_knn_prep(const float* __restrict__ x, int* __restrict__ idxOut,
                           const float* __restrict__ cw, const float* __restrict__ mlp_w,
                           const float* __restrict__ mlp_b, const float* __restrict__ f,
                           unsigned short* __restrict__ bp, unsigned short* __restrict__ bp2,
                           unsigned short* __restrict__ ft) {
  __shared__ __align__(16) unsigned char sm[66560];  // pts (64KB) | 4 transpose tiles
  int K = blockIdx.x;

  if (K >= 512) {
    // ================= prep blocks =================
    int vb = (K - 512) * 4 + (threadIdx.x >> 8);  // virtual 256-thr block 0..799
    int vt = threadIdx.x & 255;
    if (vb < 256) {
      // conv_w lower half [64][0..1023] -> bpk B-frag bf16 (K=1024)
      int t = vb * 256 + vt;  // 65536
      int j = t & 7, lane = (t >> 3) & 63, nt = (t >> 9) & 3, ks = t >> 11;
      int k = ks * 32 + ((lane >> 4) << 3) + j;
      int o = nt * 16 + (lane & 15);
      bp[t] = f2bf(cw[o * 2048 + k]);
    } else if (vb < 288) {
      // folded x_feats weights -> bpk2 B-frag bf16 (K=128)
      int t = (vb - 256) * 256 + vt;  // 8192
      int jj = t & 7, lane = (t >> 3) & 63, nt = (t >> 9) & 3, ks2 = t >> 11;
      int k = ks2 * 32 + ((lane >> 4) << 3) + jj;
      int s = k >> 3, j = k & 7;
      int o = nt * 16 + (lane & 15);
      float acc = 0.0f;
      for (int c = 0; c < 64; ++c) {
        float coef = (j < 7) ? mlp_w[c * 7 + j] : mlp_b[c];
        acc = fmaf(cw[o * 2048 + 1024 + c * 16 + s], coef, acc);
      }
      bp2[t] = f2bf(acc);
    } else {
      // feature [B][C][N] -> ftT [B][N][C] bf16 ; 4 tiles aliased in sm
      float(*tile)[65] = (float(*)[65])(sm + (threadIdx.x >> 8) * 16640);
      int blk3 = vb - 288;  // 0..511
      int b = blk3 >> 6;
      int n0 = (blk3 & 63) * 64;
      int lane = vt & 63;
      int rr = vt >> 6;  // 0..3
#pragma unroll
      for (int c0 = 0; c0 < 64; c0 += 4) {
        int c = c0 + rr;
        tile[c][lane] = f[(b * 64 + c) * 4096 + n0 + lane];
      }
      __syncthreads();
#pragma unroll
      for (int m0 = 0; m0 < 64; m0 += 4) {
        int nn = m0 + rr;
        ft[(b * 4096 + n0 + nn) * 64 + lane] = f2bf(tile[lane][nn]);
      }
    }
    return;
  }

  // ================= knn blocks (R10 core) =================
  float4* pts = (float4*)sm;
  int b = K >> 6;  // 64 blocks/batch, 64 rows/block
  const float* xb = x + b * 3 * 4096;
  for (int i = threadIdx.x; i < 4096; i += 1024) {
    float px = xb[i], py = xb[4096 + i], pz = xb[8192 + i];
    pts[i] = make_float4(px, py, pz, fmaf(px, px, fmaf(py, py, pz * pz)));
  }
  __syncthreads();

  int lane = threadIdx.x & 63;
  int w = threadIdx.x >> 6;
  int nb = ((K & 63) << 6) + (w << 2);  // first of this wave's 4 rows
  int gb = b * 4096 + nb;

  float4 q0 = pts[nb], q1 = pts[nb + 1], q2 = pts[nb + 2], q3 = pts[nb + 3];
  f32x2 m2x01 = {-2.0f * q0.x, -2.0f * q1.x};
  f32x2 m2y01 = {-2.0f * q0.y, -2.0f * q1.y};
  f32x2 m2z01 = {-2.0f * q0.z, -2.0f * q1.z};
  f32x2 m2x23 = {-2.0f * q2.x, -2.0f * q3.x};
  f32x2 m2y23 = {-2.0f * q2.y, -2.0f * q3.y};
  f32x2 m2z23 = {-2.0f * q2.z, -2.0f * q3.z};

  // ---- pass 1: per-lane min for 4 rows, packed f32 ----
  float v0 = FLT_MAX, v1 = FLT_MAX, v2 = FLT_MAX, v3 = FLT_MAX;
#pragma unroll 4
  for (int i = 0; i < 64; ++i) {
    float4 p = pts[(i << 6) | lane];
    f32x2 pxy = {p.x, p.y}, pzw = {p.z, p.w};
    f32x2 t0 = pk_fma_zw(m2z01, pzw);
    f32x2 t1 = pk_fma_zw(m2z23, pzw);
    t0 = pk_fma_s1hi(m2y01, pxy, t0);
    t1 = pk_fma_s1hi(m2y23, pxy, t1);
    t0 = pk_fma_s1lo(m2x01, pxy, t0);
    t1 = pk_fma_s1lo(m2x23, pxy, t1);
    v0 = fminf(v0, t0[0]);
    v1 = fminf(v1, t0[1]);
    v2 = fminf(v2, t1[0]);
    v3 = fminf(v3, t1[1]);
  }

  // ---- FULL bitonic sort of the 64 lane minima (ascending) ----
#pragma unroll
  for (int k = 2; k <= 64; k <<= 1) {
#pragma unroll
    for (int j = k >> 1; j > 0; j >>= 1) {
      bool sel = ((lane & k) == 0) == ((lane & j) == 0);
      {
        float o = __shfl_xor(v0, j, 64);
        v0 = sel ? fminf(v0, o) : fmaxf(v0, o);
      }
      {
        float o = __shfl_xor(v1, j, 64);
        v1 = sel ? fminf(v1, o) : fmaxf(v1, o);
      }
      {
        float o = __shfl_xor(v2, j, 64);
        v2 = sel ? fminf(v2, o) : fmaxf(v2, o);
      }
      {
        float o = __shfl_xor(v3, j, 64);
        v3 = sel ? fminf(v3, o) : fmaxf(v3, o);
      }
    }
  }
  float T0 = __shfl(v0, 23, 64);  // exact pk-rank-24 of lane minima
  float T1 = __shfl(v1, 23, 64);
  float T2 = __shfl(v2, 23, 64);
  float T3 = __shfl(v3, 23, 64);

  // ---- pass 2: identical pk chain, ballot/ds_permute compaction per row ----
  int ei0 = -1, ei1 = -1, ei2 = -1, ei3 = -1;
  int base0 = 0, base1 = 0, base2 = 0, base3 = 0;
  bool ovf0 = false, ovf1 = false, ovf2 = false, ovf3 = false;
#pragma unroll 2
  for (int i = 0; i < 64; ++i) {
    int j = (i << 6) | lane;
    float4 p = pts[j];
    f32x2 pxy = {p.x, p.y}, pzw = {p.z, p.w};
    f32x2 t0 = pk_fma_zw(m2z01, pzw);
    f32x2 t1 = pk_fma_zw(m2z23, pzw);
    t0 = pk_fma_s1hi(m2y01, pxy, t0);
    t1 = pk_fma_s1hi(m2y23, pxy, t1);
    t0 = pk_fma_s1lo(m2x01, pxy, t0);
    t1 = pk_fma_s1lo(m2x23, pxy, t1);
    {
      bool pred = (t0[0] <= T0);
      unsigned long long mask = __ballot(pred);
      if (mask) {
        int cnt = __popcll(mask);
        if (base0 + cnt > 63) {
          ovf0 = true;
        } else {
          int dst = pred ? (base0 + __popcll(mask & ((1ull << lane) - 1ull))) : 63;
          int got = __builtin_amdgcn_ds_permute(dst << 2, j);
          bool recv = (lane >= base0) && (lane < base0 + cnt);
          ei0 = recv ? got : ei0;
        }
        base0 += cnt;
      }
    }
    {
      bool pred = (t0[1] <= T1);
      unsigned long long mask = __ballot(pred);
      if (mask) {
        int cnt = __popcll(mask);
        if (base1 + cnt > 63) {
          ovf1 = true;
        } else {
          int dst = pred ? (base1 + __popcll(mask & ((1ull << lane) - 1ull))) : 63;
          int got = __builtin_amdgcn_ds_permute(dst << 2, j);
          bool recv = (lane >= base1) && (lane < base1 + cnt);
          ei1 = recv ? got : ei1;
        }
        base1 += cnt;
      }
    }
    {
      bool pred = (t1[0] <= T2);
      unsigned long long mask = __ballot(pred);
      if (mask) {
        int cnt = __popcll(mask);
        if (base2 + cnt > 63) {
          ovf2 = true;
        } else {
          int dst = pred ? (base2 + __popcll(mask & ((1ull << lane) - 1ull))) : 63;
          int got = __builtin_amdgcn_ds_permute(dst << 2, j);
          bool recv = (lane >= base2) && (lane < base2 + cnt);
          ei2 = recv ? got : ei2;
        }
        base2 += cnt;
      }
    }
    {
      bool pred = (t1[1] <= T3);
      unsigned long long mask = __ballot(pred);
      if (mask) {
        int cnt = __popcll(mask);
        if (base3 + cnt > 63) {
          ovf3 = true;
        } else {
          int dst = pred ? (base3 + __popcll(mask & ((1ull << lane) - 1ull))) : 63;
          int got = __builtin_amdgcn_ds_permute(dst << 2, j);
          bool recv = (lane >= base3) && (lane < base3 + cnt);
          ei3 = recv ? got : ei3;
        }
        base3 += cnt;
      }
    }
  }

  // ---- exact f64 lex rank (readlane broadcast, 4 rows fused) ----
  int c[4], e[4];
  c[0] = ovf0 ? 0 : base0;
  c[1] = ovf1 ? 0 : base1;
  c[2] = ovf2 ? 0 : base2;
  c[3] = ovf3 ? 0 : base3;
  e[0] = ei0;
  e[1] = ei1;
  e[2] = ei2;
  e[3] = ei3;
  int rank0 = 0, rank1 = 0, rank2 = 0, rank3 = 0;
  double dm[4];
#pragma unroll
  for (int r = 0; r < 4; ++r) {
    int e_ = (lane < c[r]) ? e[r] : 0;
    e[r] = e_;
    float4 pp = pts[e_];
    float4 qq = pts[nb + r];
    double dx = (double)pp.x - (double)qq.x;
    double dy = (double)pp.y - (double)qq.y;
    double dz = (double)pp.z - (double)qq.z;
    dm[r] = dx * dx + dy * dy + dz * dz;
  }
  int cmax = max(max(c[0], c[1]), max(c[2], c[3]));
  for (int it = 0; it < cmax; ++it) {
#pragma unroll
    for (int r = 0; r < 4; ++r) {
      int lo = __builtin_amdgcn_readlane(__double2loint(dm[r]), it);
      int hi = __builtin_amdgcn_readlane(__double2hiint(dm[r]), it);
      int ir = __builtin_amdgcn_readlane(e[r], it);
      double dr = __hiloint2double(hi, lo);
      bool less = (it < c[r]) && ((dr < dm[r]) || (dr == dm[r] && ir < e[r]));
      int inc = (lane < c[r] && less) ? 1 : 0;
      if (r == 0) rank0 += inc;
      else if (r == 1) rank1 += inc;
      else if (r == 2) rank2 += inc;
      else rank3 += inc;
    }
  }
#pragma unroll
  for (int r = 0; r < 4; ++r) {
    int rk = (r == 0) ? rank0 : (r == 1) ? rank1 : (r == 2) ? rank2 : rank3;
    bool kept = (lane < c[r]) && (rk < 20);
    bool selfk = kept && (e[r] == nb + r);
    if (__ballot(selfk) != 0ull) {
      if (kept) idxOut[(gb + r) * 20 + rk] = e[r];
    } else {
      knn_full(pts, nb + r, lane, gb + r, idxOut);
    }
  }
}

// ---------- K2: fused features + aw(bf16 B-frag) + MFMA agg + MFMA conv ----------
#define AGG_OFF 0            // bf16 agg[8][1024], 16KB; reused as f32 red
#define AWB_OFF 16384        // bf16 awB[8][512]  B-frag (32k x 16s per pt), 8KB
#define FPA_OFF 24576        // bf16 fpA[16][128] F' A-tile, 4KB
#define F7S_OFF 28672        // float4 f7s[8][20], 2560B
#define QL_OFF  31232        // float4 qL[8], 128B
#define IDX_OFF 31360        // int idxL[8][20], 640B
#define SMEM_SZ 33792        // 33KB total

__launch_bounds__(256, 4)
__global__ void k_main(const float* __restrict__ x, const float* __restrict__ feat,
                       const unsigned short* __restrict__ ftT, int useFtT,
                       const float* __restrict__ kern,
                       const unsigned short* __restrict__ bpk,
                       const unsigned short* __restrict__ bpk2,
                       const float* __restrict__ conv_b, const int* __restrict__ idxIn,
                       float* __restrict__ out) {
  __shared__ __align__(16) unsigned char smem[SMEM_SZ];
  unsigned short* agg = (unsigned short*)(smem + AGG_OFF);
  unsigned short* awB = (unsigned short*)(smem + AWB_OFF);
  float4* f7s = (float4*)(smem + F7S_OFF);
  float4* qL = (float4*)(smem + QL_OFF);
  int* idxL = (int*)(smem + IDX_OFF);

  int t = threadIdx.x;
  int lane = t & 63;
  int w = t >> 6;
  int b = blockIdx.x & 7;
  int n0 = (blockIdx.x >> 3) * BPTS;
  int g0 = b * 4096 + n0;
  const float* xb = x + b * 3 * 4096;

  // ---- step 0: geometry (8 pts x 20 nbrs) ----
  {
    int pt = t >> 5, slot = t & 31;
    int n = n0 + pt;
    float qx = xb[n], qy = xb[4096 + n], qz = xb[8192 + n];
    if (slot < 20) {
      int kk = idxIn[(g0 + pt) * 20 + slot];
      idxL[pt * 20 + slot] = kk;
      float rx = xb[kk] - qx, ry = xb[4096 + kk] - qy, rz = xb[8192 + kk] - qz;
      float ds = sqrtf(rx * rx + ry * ry + rz * rz);
      f7s[pt * 20 + slot] = make_float4(rx, ry, rz, ds);
    } else if (slot == 20) {
      qL[pt] = make_float4(qx, qy, qz, 0.0f);
    }
  }
  __syncthreads();

  // ---- step 1: aw chain -> awB bf16 B-frag + F' build (128 thr: (pt,s)) ----
  if (t < 128) {
    int pt = t >> 4, s = t & 15;
    float kx = kern[s], ky = kern[16 + s], kz = kern[32 + s];
    float wv[20];
#pragma unroll
    for (int k = 0; k < 20; ++k) {
      float4 f = f7s[pt * 20 + k];
      float dot = f.x * kx + f.y * ky + f.z * kz;
      if (s == 0 && k == 0) dot += 1.0f;
      wv[k] = dot > 0.0f ? dot : 0.0f;
    }
    float sum = 0.0f;
#pragma unroll
    for (int k = 0; k < 20; ++k) sum += wv[k];
    float inv1 = 1.0f / (sum + 1e-6f);
    float sum2 = 0.0f;
#pragma unroll
    for (int k = 0; k < 20; ++k) {
      float u = wv[k] * inv1;
      sum2 += u * u;
    }
    float inv2 = 1.0f / (sum2 + 1e-6f);
    float colsum = 0.0f;
    float F0 = 0.0f, F1 = 0.0f, F2 = 0.0f, F3 = 0.0f;
    unsigned short* awp = awB + pt * 512;
#pragma unroll
    for (int k = 0; k < 20; ++k) {
      float u = wv[k] * inv1;
      u = u * u * inv2;
      u = (u > 0.1f) ? u : 0.0f;
      awp[(((k >> 3) * 16 + s) << 3) + (k & 7)] = f2bf(u);
      colsum += u;
      float4 f = f7s[pt * 20 + k];
      F0 = fmaf(f.x, u, F0);
      F1 = fmaf(f.y, u, F1);
      F2 = fmaf(f.z, u, F2);
      F3 = fmaf(f.w, u, F3);
    }
#pragma unroll
    for (int k = 20; k < 32; ++k)
      awp[(((k >> 3) * 16 + s) << 3) + (k & 7)] = 0;
    float4 q = qL[pt];
    __align__(16) unsigned short tmp[8];
    tmp[0] = f2bf(q.x * colsum);
    tmp[1] = f2bf(q.y * colsum);
    tmp[2] = f2bf(q.z * colsum);
    tmp[3] = f2bf(F0);
    tmp[4] = f2bf(F1);
    tmp[5] = f2bf(F2);
    tmp[6] = f2bf(F3);
    tmp[7] = f2bf(colsum);
    *(uint4*)(smem + FPA_OFF + pt * 256 + ((s ^ (pt & 7)) << 4)) = *(uint4*)tmp;
  }
  __syncthreads();

  // ---- agg via MFMA: per pt, [64c x 32k(pad)] x [32k x 16s] ----
  {
    int r15 = lane & 15, chunk = lane >> 4;
#pragma unroll
    for (int half = 0; half < 2; ++half) {
      int pt = (w << 1) + half;
      int nofs[8];
#pragma unroll
      for (int j = 0; j < 8; ++j) {
        int k = (chunk << 3) + j;
        nofs[j] = (k < 20) ? ((b * 4096 + idxL[pt * 20 + k]) << 6) : -1;
      }
      short8 bfrag = *(const short8*)(awB + pt * 512 + (lane << 3));
      f32x4 accA[4];
#pragma unroll
      for (int ct = 0; ct < 4; ++ct) accA[ct] = (f32x4){0.f, 0.f, 0.f, 0.f};
#pragma unroll
      for (int ct = 0; ct < 4; ++ct) {
        int c = (ct << 4) + r15;
        union { short8 v; unsigned short u[8]; } af;
#pragma unroll
        for (int j = 0; j < 8; ++j) {
          unsigned short val = 0;
          if (nofs[j] >= 0) {
            if (useFtT) val = ftT[nofs[j] + c];
            else val = f2bf(feat[(b * 64 + c) * 4096 + (nofs[j] >> 6) - b * 4096]);
          }
          af.u[j] = val;
        }
        accA[ct] = __builtin_amdgcn_mfma_f32_16x16x32_bf16(af.v, bfrag, accA[ct], 0, 0, 0);
      }
      char* rb = (char*)(smem + AGG_OFF) + pt * 2048;
      int sw = (pt & 7) << 4;
#pragma unroll
      for (int ct = 0; ct < 4; ++ct)
#pragma unroll
        for (int q = 0; q < 4; ++q) {
          int kidx = (((ct << 4) + (chunk << 2) + q) << 4) + r15;
          *(unsigned short*)(rb + ((kidx << 1) ^ sw)) = f2bf(accA[ct][q]);
        }
    }
  }
  __syncthreads();

  // ---- conv GEMM: K=1024 (agg) + K=128 (F') ----
  f32x4 acc[4];
#pragma unroll
  for (int nt = 0; nt < 4; ++nt) acc[nt] = (f32x4){0.f, 0.f, 0.f, 0.f};
  {
    int r = lane & 15;
    const char* rowbase = (const char*)(smem + AGG_OFF) + r * 2048;
#pragma unroll
    for (int ks = 0; ks < 8; ++ks) {
      int ksl = w * 8 + ks;
      int off = (ksl * 64 + ((lane >> 4) << 4)) ^ ((r & 7) << 4);
      short8 af = *(const short8*)(rowbase + off);
#pragma unroll
      for (int nt = 0; nt < 4; ++nt) {
        short8 bf = *(const short8*)(bpk + (((ksl * 4 + nt) * 64 + lane) << 3));
        acc[nt] = __builtin_amdgcn_mfma_f32_16x16x32_bf16(af, bf, acc[nt], 0, 0, 0);
      }
    }
    {
      int chunk = (w << 2) + (lane >> 4);  // 0..15
      short8 af = *(const short8*)(smem + FPA_OFF + r * 256 + ((chunk ^ (r & 7)) << 4));
#pragma unroll
      for (int nt = 0; nt < 4; ++nt) {
        short8 bf = *(const short8*)(bpk2 + ((((w << 2) + nt) * 64 + lane) << 3));
        acc[nt] = __builtin_amdgcn_mfma_f32_16x16x32_bf16(af, bf, acc[nt], 0, 0, 0);
      }
    }
  }
  __syncthreads();  // before reusing agg as red

  // ---- cross-wave reduce ----
  float* red = (float*)(smem + AGG_OFF);  // 8KB of 16KB
  {
#pragma unroll
    for (int nt = 0; nt < 4; ++nt)
#pragma unroll
      for (int r = 0; r < 4; ++r) {
        int row = ((lane >> 4) << 2) + r;  // 0..15; only 0..7 valid
        if (row < 8) {
          int o = nt * 16 + (lane & 15);
          red[(w * 8 + row) * 64 + (o ^ ((row & 7) << 2))] = acc[nt][r];
        }
      }
  }
  __syncthreads();
#pragma unroll
  for (int rep = 0; rep < 2; ++rep) {
    int u = rep * 256 + t;
    int pt = u & 7, o = u >> 3;
    float s = conv_b[o];
#pragma unroll
    for (int w2 = 0; w2 < 4; ++w2) s += red[(w2 * 8 + pt) * 64 + (o ^ ((pt & 7) << 2))];
    out[(b * 64 + o) * 4096 + n0 + pt] = s;
  }
}

// ---------- K3a: BN stats stage 1 (512 blocks) ----------
__global__ void k_bnstats1(const float* __restrict__ out, double* __restrict__ partial) {
  __shared__ double rs[256], rq[256];
  int o = blockIdx.x & 63, b = blockIdx.x >> 6;
  const float* p = out + (b * 64 + o) * 4096;
  double s = 0.0, q = 0.0;
  for (int i = threadIdx.x; i < 4096; i += 256) {
    double v = (double)p[i];
    s += v;
    q += v * v;
  }
  rs[threadIdx.x] = s;
  rq[threadIdx.x] = q;
  __syncthreads();
  for (int st = 128; st > 0; st >>= 1) {
    if ((int)threadIdx.x < st) {
      rs[threadIdx.x] += rs[threadIdx.x + st];
      rq[threadIdx.x] += rq[threadIdx.x + st];
    }
    __syncthreads();
  }
  if (threadIdx.x == 0) {
    partial[(o * 8 + b) * 2] = rs[0];
    partial[(o * 8 + b) * 2 + 1] = rq[0];
  }
}

// ---------- K3b: BN apply with inline stage-2 (each block = one channel o) ----------
__global__ void k_bnapply(float* __restrict__ out, const double* __restrict__ partial,
                          const float* __restrict__ gamma, const float* __restrict__ beta) {
  __shared__ float sc_sh[2];
  int o = (blockIdx.x >> 2) & 63;  // each block's 256 float4s lie in one channel
  if (threadIdx.x == 0) {
    double s = 0.0, q = 0.0;
#pragma unroll
    for (int b = 0; b < 8; ++b) {
      s += partial[(o * 8 + b) * 2];
      q += partial[(o * 8 + b) * 2 + 1];
    }
    double mean = s / 32768.0;
    double var = q / 32768.0 - mean * mean;
    double inv = 1.0 / sqrt(var + 1e-5);
    double sc = (double)gamma[o] * inv;
    sc_sh[0] = (float)sc;
    sc_sh[1] = (float)((double)beta[o] - mean * sc);
  }
  __syncthreads();
  int i4 = blockIdx.x * 256 + threadIdx.x;  // 524288 float4s
  float sc = sc_sh[0], sh = sc_sh[1];
  float4 v = ((const float4*)out)[i4];
  v.x = fmaf(v.x, sc, sh);
  v.y = fmaf(v.y, sc, sh);
  v.z = fmaf(v.z, sc, sh);
  v.w = fmaf(v.w, sc, sh);
  ((float4*)out)[i4] = v;
}

extern "C" void kernel_launch(void* const* d_in, const int* in_sizes, int n_in,
                              void* d_out, int out_size, void* d_ws, size_t ws_size,
                              hipStream_t stream) {
  const float* x = (const float*)d_in[0];
  const float* feat = (const float*)d_in[1];
  const float* kern = (const float*)d_in[2];
  const float* mlp_w = (const float*)d_in[3];
  const float* mlp_b = (const float*)d_in[4];
  const float* conv_w = (const float*)d_in[5];
  const float* conv_b = (const float*)d_in[6];
  const float* gamma = (const float*)d_in[7];
  const float* beta = (const float*)d_in[8];
  float* out = (float*)d_out;
  char* ws = (char*)d_ws;

  // workspace layout
  int* idx = (int*)ws;                                    // 0 .. 2,621,440
  double* partial = (double*)(ws + 2621440);              // 8,192 B
  unsigned short* bpk = (unsigned short*)(ws + 2633728);  // 131,072 B (K=1024)
  unsigned short* bpk2 = (unsigned short*)(ws + 2764800); // 16,384 B  (K=128)
  unsigned short* ftT = (unsigned short*)(ws + 2781184);  // 4,194,304 B
  int useFtT = (ws_size >= (size_t)(2781184 + 4194304)) ? 1 : 0;

  k_knn_prep<<<712, 1024, 0, stream>>>(x, idx, conv_w, mlp_w, mlp_b, feat,
                                       bpk, bpk2, ftT);
  k_main<<<4096, 256, 0, stream>>>(x, feat, ftT, useFtT, kern, bpk, bpk2,
                                   conv_b, idx, out);
  k_bnstats1<<<512, 256, 0, stream>>>(out, partial);
  k_bnapply<<<2048, 256, 0, stream>>>(out, partial, gamma, beta);
}